// Round 10
// baseline (562.839 us; speedup 1.0000x reference)
//
#include <hip/hip_runtime.h>

// ScoreNetGNN: B=50000 graphs x 7 nodes, fully-connected (42 edges/graph).
// R6: MFMA pipeline (16x16x32 bf16 split hi+lo). R7: strides/LDS. R8: two
// graphs/wave. R9: 128-thr blocks, de-resident B. R10: LDS-pipe attack —
// edge groups padded to 8 rows (7 chunks of 16 = 2 groups/chunk); max-agg
// done IN REGISTERS (rr-max + shfl_xor(16)) so edgeconv never round-trips
// C through LDS; result written directly into next layer's X; L3b reduces
// in-register and stores straight to global (S strip + gather deleted).
// G0/G1/XS2 ping-pong regions, 23040 B/block (7 blocks/CU LDS-wise).
// f32 I/O hardcoded (R3 counters: WRITE_SIZE = 4 B/elem).

#define NB 50000

typedef unsigned short u16;
typedef short short8 __attribute__((ext_vector_type(8)));
typedef float f32x4 __attribute__((ext_vector_type(4)));

// d_ws fragment offsets (u16 units). frag stride 1024 u16 (hi 512 | lo 512),
// lane entry = 8 u16 (16B). Total 94208 u16 = 188416 bytes.
#define OFF_I  0
#define OFF_1A 8192
#define OFF_2A 24576
#define OFF_3A 49152
#define OFF_1B 73728
#define OFF_2B 81920
#define OFF_WT 90112
#define OFF_3B 92160

// LDS per-wave geometry (bytes). G0/G1: 16 rows x 64 bf16 @ stride 144
// (36 dw == 4 mod 32 -> worst 2-way, free), hi [0,2304) lo [2304,4608).
// Used alternately for X, H, and S (f32 C-buffer @ stride 276; 69 dw ->
// <=2-way). XS2: xs strip 16 x 32 bf16 @ stride 72, hi/lo planes, write-once.
#define HSTR 144
#define HLO  2304
#define SSTR 276
#define XS2S 72
#define XS2LO 1152
#define WREG 11520   // G0 4608 + G1 4608 + XS2 2304

__device__ __forceinline__ float b2f(u16 u) {
    return __uint_as_float(((unsigned int)u) << 16);
}
__device__ __forceinline__ u16 f2b(float f) {
    unsigned int u = __float_as_uint(f);
    u += 0x7FFFu + ((u >> 16) & 1u);   // RNE
    return (u16)(u >> 16);
}
__device__ __forceinline__ float bcast(float v, int l) {
    return __uint_as_float(__builtin_amdgcn_readlane(__float_as_uint(v), l));
}

// ---- setup: pack weights into split-bf16 MFMA B-fragments ----
__global__ __launch_bounds__(128) void pack_kernel(
    const float* __restrict__ wi2, const float* __restrict__ w1a,
    const float* __restrict__ w2a, const float* __restrict__ w3a,
    const float* __restrict__ w1b, const float* __restrict__ w2b,
    const float* __restrict__ wt,  const float* __restrict__ w3b,
    u16* __restrict__ ws)
{
    int blk = blockIdx.x;
    int half = threadIdx.x >> 6;          // 0 = hi, 1 = lo
    int lane = threadIdx.x & 63;
    if (blk < 88) {
        const float* src; int NT, qoff, obase, frag;
        if (blk < 8)       { src = wi2; NT = 4; qoff = 0;  obase = OFF_I;  frag = blk;      }
        else if (blk < 24) { src = w1a; NT = 8; qoff = 64; obase = OFF_1A; frag = blk - 8;  }
        else if (blk < 48) { src = w2a; NT = 8; qoff = 96; obase = OFF_2A; frag = blk - 24; }
        else if (blk < 72) { src = w3a; NT = 8; qoff = 96; obase = OFF_3A; frag = blk - 48; }
        else if (blk < 80) { src = w1b; NT = 4; qoff = 0;  obase = OFF_1B; frag = blk - 72; }
        else               { src = w2b; NT = 4; qoff = 0;  obase = OFF_2B; frag = blk - 80; }
        int kt = frag / NT, nt = frag % NT;
        int k0 = kt * 32 + (lane >> 4) * 8;
        int n  = nt * 16 + (lane & 15);
        u16* dst = ws + obase + frag * 1024 + half * 512 + lane * 8;
#pragma unroll
        for (int j = 0; j < 8; ++j) {
            int k = k0 + j;
            int idx = (n < 64) ? (k * 64 + n) : ((qoff + k) * 64 + (n - 64));
            float v = src[idx];
            u16 hi = f2b(v);
            dst[j] = (half == 0) ? hi : f2b(v - b2f(hi));
        }
    } else if (blk < 90) {               // wt (32,32): 2 n-frags
        int frag = blk - 88;
        int k0 = (lane >> 4) * 8;
        int n  = frag * 16 + (lane & 15);
        u16* dst = ws + OFF_WT + frag * 1024 + half * 512 + lane * 8;
#pragma unroll
        for (int j = 0; j < 8; ++j) {
            float v = wt[(k0 + j) * 32 + n];
            u16 hi = f2b(v);
            dst[j] = (half == 0) ? hi : f2b(v - b2f(hi));
        }
    } else {                             // w3b (64,3): 2 k-frags, cols 3..15 = 0
        int frag = blk - 90;
        int k0 = frag * 32 + (lane >> 4) * 8;
        int n  = lane & 15;
        u16* dst = ws + OFF_3B + frag * 1024 + half * 512 + lane * 8;
#pragma unroll
        for (int j = 0; j < 8; ++j) {
            float v = (n < 3) ? w3b[(k0 + j) * 3 + n] : 0.f;
            u16 hi = f2b(v);
            dst[j] = (half == 0) ? hi : f2b(v - b2f(hi));
        }
    }
}

__device__ __forceinline__ f32x4 mfma3(short8 ah, short8 al, short8 bh, short8 bl, f32x4 acc) {
    acc = __builtin_amdgcn_mfma_f32_16x16x32_bf16(ah, bh, acc, 0, 0, 0);
    acc = __builtin_amdgcn_mfma_f32_16x16x32_bf16(ah, bl, acc, 0, 0, 0);
    acc = __builtin_amdgcn_mfma_f32_16x16x32_bf16(al, bh, acc, 0, 0, 0);
    return acc;   // lo*lo dropped (~2^-18 rel)
}

// node k (0..13) -> row (g0 rows 0-6, g1 rows 8-14; rows 7,15 stale/unread)
#define ROW(k) ((k) < 7 ? (k) : (k) + 1)

// write 14 node values (64 cols) into region G as X
__device__ __forceinline__ void writeX64_14(char* G, int L, const float* v) {
#pragma unroll
    for (int k = 0; k < 14; ++k) {
        int r = ROW(k);
        u16 hi = f2b(v[k]);
        *(u16*)(G + r * HSTR + L * 2) = hi;
        *(u16*)(G + HLO + r * HSTR + L * 2) = f2b(v[k] - b2f(hi));
    }
}
// A-frags: kt 0,1 from G (cols 0-63); kt 2 from XS2 strip (cols 64-95)
template<int KT>
__device__ __forceinline__ void loadA(const char* G, const char* XS2, int L,
                                      short8* Ah, short8* Al) {
#pragma unroll
    for (int kt = 0; kt < KT; ++kt) {
        if (kt < 2) {
            Ah[kt] = *(const short8*)(G + (L & 15) * HSTR + kt * 64 + (L >> 4) * 16);
            Al[kt] = *(const short8*)(G + HLO + (L & 15) * HSTR + kt * 64 + (L >> 4) * 16);
        } else {
            Ah[kt] = *(const short8*)(XS2 + (L & 15) * XS2S + (L >> 4) * 16);
            Al[kt] = *(const short8*)(XS2 + XS2LO + (L & 15) * XS2S + (L >> 4) * 16);
        }
    }
}
// One 4-N-tile GEMM pass: S[row][col 0..63] = A(16xK) @ B(Kx64), S in region Sg
template<int KT, int NT>
__device__ __forceinline__ void lin_pass(const u16* __restrict__ ws, int off, int nt0,
                                         const short8* Ah, const short8* Al,
                                         char* Sg, int L) {
#pragma unroll
    for (int ntc = 0; ntc < 4; ++ntc) {
        f32x4 acc = {0.f, 0.f, 0.f, 0.f};
#pragma unroll
        for (int kt = 0; kt < KT; ++kt) {
            int f = kt * NT + nt0 + ntc;
            short8 bh = *(const short8*)(ws + off + f * 1024 + L * 8);
            short8 bl = *(const short8*)(ws + off + f * 1024 + 512 + L * 8);
            acc = mfma3(Ah[kt], Al[kt], bh, bl, acc);
        }
#pragma unroll
        for (int rr = 0; rr < 4; ++rr)   // C: row=(L>>4)*4+rr, col=ntc*16+(L&15)
            *(float*)(Sg + ((L >> 4) * 4 + rr) * SSTR + ntc * 64 + (L & 15) * 4) = acc[rr];
    }
}
__device__ __forceinline__ void readS14(const char* Sg, int L, float* o) {
#pragma unroll
    for (int k = 0; k < 14; ++k) o[k] = *(const float*)(Sg + ROW(k) * SSTR + L * 4);
}
// stage 16 edge rows (chunk c of 7): 2 groups of 8 rows; rows 6,7 of each
// group duplicate edge 0 (max-safe padding). hv = relu(pp_i + qq_j).
__device__ __forceinline__ void stageH2(char* G, int c, const float* pp, const float* qq, int L) {
#pragma unroll
    for (int r = 0; r < 16; ++r) {
        int gidx = c * 2 + (r >> 3);          // 0..13
        int gb = (gidx >= 7) ? 1 : 0;
        int i = gidx - gb * 7;
        int rg = r & 7;
        int jj = (rg < 6) ? rg : 0;
        int j = jj + (jj >= i);
        float hv = fmaxf(pp[gb * 7 + i] + qq[gb * 7 + j], 0.f);
        u16 hi = f2b(hv);
        *(u16*)(G + r * HSTR + L * 2) = hi;
        *(u16*)(G + HLO + r * HSTR + L * 2) = f2b(hv - b2f(hi));
    }
}
__device__ __forceinline__ void loadAH(const char* G, int L,
                                       short8& Ah0, short8& Ah1, short8& Al0, short8& Al1) {
    Ah0 = *(const short8*)(G + (L & 15) * HSTR + (L >> 4) * 16);
    Ah1 = *(const short8*)(G + (L & 15) * HSTR + 64 + (L >> 4) * 16);
    Al0 = *(const short8*)(G + HLO + (L & 15) * HSTR + (L >> 4) * 16);
    Al1 = *(const short8*)(G + HLO + (L & 15) * HSTR + 64 + (L >> 4) * 16);
}

// EdgeConv second linear (64->64) + IN-REGISTER max-agg + bias + relu.
// H staged in Ghreg; output X written directly into Gxout (hi: quads 0/2,
// lo: quads 1/3 after shfl_xor(16) broadcast of the group max).
__device__ __forceinline__ void edgeconv3(const u16* __restrict__ ws, int offB,
                                          char* Ghreg, char* Gxout,
                                          const float* pp, const float* qq,
                                          const float* bb, int L) {
    int q = L >> 4;
#pragma unroll
    for (int c = 0; c < 7; ++c) {
        stageH2(Ghreg, c, pp, qq, L);
        short8 Ah0, Ah1, Al0, Al1;
        loadAH(Ghreg, L, Ah0, Ah1, Al0, Al1);
        int gidx = c * 2 + (q >> 1);
        int gb = (gidx >= 7) ? 1 : 0;
        int xrow = gidx + gb;               // ROW(gidx)
#pragma unroll
        for (int nt = 0; nt < 4; ++nt) {
            short8 bh0 = *(const short8*)(ws + offB + nt * 1024 + L * 8);
            short8 bl0 = *(const short8*)(ws + offB + nt * 1024 + 512 + L * 8);
            short8 bh1 = *(const short8*)(ws + offB + (4 + nt) * 1024 + L * 8);
            short8 bl1 = *(const short8*)(ws + offB + (4 + nt) * 1024 + 512 + L * 8);
            f32x4 acc = {0.f, 0.f, 0.f, 0.f};
            acc = mfma3(Ah0, Al0, bh0, bl0, acc);
            acc = mfma3(Ah1, Al1, bh1, bl1, acc);
            float m = fmaxf(fmaxf(acc[0], acc[1]), fmaxf(acc[2], acc[3]));
            m = fmaxf(m, __shfl_xor(m, 16, 64));   // group max across quad pair
            float xv = fmaxf(m + bb[nt], 0.f);
            u16 hi = f2b(xv);
            u16 w = (q & 1) ? f2b(xv - b2f(hi)) : hi;
            int plane = (q & 1) ? HLO : 0;
            *(u16*)(Gxout + plane + xrow * HSTR + (nt * 16 + (L & 15)) * 2) = w;
        }
    }
}

__global__ __launch_bounds__(128) void gnn_kernel(
    const float* __restrict__ omega, const float* __restrict__ tt, const float* __restrict__ Wf,
    const float* __restrict__ wi1, const float* __restrict__ bi1, const float* __restrict__ bi2,
    const float* __restrict__ bt,
    const float* __restrict__ b1a, const float* __restrict__ b1b,
    const float* __restrict__ b2a, const float* __restrict__ b2b,
    const float* __restrict__ b3a, const float* __restrict__ b3b,
    const u16* __restrict__ ws, float* __restrict__ out)
{
    __shared__ __align__(16) char smem[2 * WREG];   // 23040 B/block
    const int L   = threadIdx.x & 63;
    const int wav = threadIdx.x >> 6;
    const int p   = blockIdx.x * 2 + wav;    // graph pair id, grid covers 25000
    const int g0  = p * 2;
    const int base0 = g0 * 7;                // g1 nodes start at base0+7
    char* G0  = smem + wav * WREG;
    char* G1  = G0 + 4608;
    char* XS2 = G0 + 9216;

    // ---- h1 = relu(omega@wi1 + bi1), both graphs (42 contiguous coords) ----
    float omv = (L < 42) ? omega[base0 * 3 + L] : 0.f;
    float vwi10 = wi1[L], vwi11 = wi1[64 + L], vwi12 = wi1[128 + L];
    float vbi1 = bi1[L];
    float h1[14];
#pragma unroll
    for (int k = 0; k < 14; ++k) {
        float a0 = bcast(omv, 3 * k), a1 = bcast(omv, 3 * k + 1), a2 = bcast(omv, 3 * k + 2);
        h1[k] = fmaxf(fmaf(a0, vwi10, fmaf(a1, vwi11, fmaf(a2, vwi12, vbi1))), 0.f);
    }

    // ---- time embedding via MFMA (tile-bug: node n uses t[n % B]) ----
    // E staged in G0 (cols 0-31); C -> G1; xs written ONCE to XS2.
    {
        int cc = L & 31;
        float vwf = Wf[cc & 15] * 6.283185307179586f;
        int tb = base0 - (base0 / NB) * NB;        // base0 % NB
#pragma unroll
        for (int k = 0; k < 14; ++k) {
            int ti = tb + k; if (ti >= NB) ti -= NB;
            float pj = tt[ti] * vwf;
            float remb = fmaxf((cc < 16) ? sinf(pj) : cosf(pj), 0.f);
            u16 hi = f2b(remb);
            if (L < 32) *(u16*)(G0 + ROW(k) * HSTR + cc * 2) = hi;
            else *(u16*)(G0 + HLO + ROW(k) * HSTR + cc * 2) = f2b(remb - b2f(hi));
        }
        short8 Eh = *(const short8*)(G0 + (L & 15) * HSTR + (L >> 4) * 16);
        short8 El = *(const short8*)(G0 + HLO + (L & 15) * HSTR + (L >> 4) * 16);
#pragma unroll
        for (int nt = 0; nt < 2; ++nt) {
            short8 bh = *(const short8*)(ws + OFF_WT + nt * 1024 + L * 8);
            short8 bl = *(const short8*)(ws + OFF_WT + nt * 1024 + 512 + L * 8);
            f32x4 acc = {0.f, 0.f, 0.f, 0.f};
            acc = mfma3(Eh, El, bh, bl, acc);
#pragma unroll
            for (int rr = 0; rr < 4; ++rr)
                *(float*)(G1 + ((L >> 4) * 4 + rr) * SSTR + nt * 64 + (L & 15) * 4) = acc[rr];
        }
        float vbt = bt[cc];
#pragma unroll
        for (int k = 0; k < 14; ++k) {
            float xv = fmaxf(*(const float*)(G1 + ROW(k) * SSTR + cc * 4) + vbt, 0.f);
            u16 hi = f2b(xv);
            if (L < 32) *(u16*)(XS2 + ROW(k) * XS2S + cc * 2) = hi;
            else *(u16*)(XS2 + XS2LO + ROW(k) * XS2S + cc * 2) = f2b(xv - b2f(hi));
        }
    }

    short8 Ah[3], Al[3];
    float pp[14], qq[14];

    // ---- init: x0 = h1 @ wi2 + bi2  (X: G0, S: G1, X back to G0) ----
    writeX64_14(G0, L, h1);
    loadA<2>(G0, XS2, L, Ah, Al);
    lin_pass<2, 4>(ws, OFF_I, 0, Ah, Al, G1, L);
    {
        float xh[14];
        readS14(G1, L, xh);
        float vbi2 = bi2[L];
#pragma unroll
        for (int k = 0; k < 14; ++k) xh[k] += vbi2;
        writeX64_14(G0, L, xh);
    }

    // ---- L1a (K=64): A from G0, S in G1 ----
    loadA<2>(G0, XS2, L, Ah, Al);
    lin_pass<2, 8>(ws, OFF_1A, 0, Ah, Al, G1, L);
    readS14(G1, L, pp);
    lin_pass<2, 8>(ws, OFF_1A, 4, Ah, Al, G1, L);
    readS14(G1, L, qq);
    float vb1a = b1a[L];
#pragma unroll
    for (int k = 0; k < 14; ++k) pp[k] = pp[k] + vb1a - qq[k];
    // ---- L1b: H in G0, X out -> G1 ----
    {
        float bb[4];
#pragma unroll
        for (int nt = 0; nt < 4; ++nt) bb[nt] = b1b[nt * 16 + (L & 15)];
        edgeconv3(ws, OFF_1B, G0, G1, pp, qq, bb, L);
    }

    // ---- L2a (K=96): A from G1 + XS2, S in G0 ----
    loadA<3>(G1, XS2, L, Ah, Al);
    lin_pass<3, 8>(ws, OFF_2A, 0, Ah, Al, G0, L);
    readS14(G0, L, pp);
    lin_pass<3, 8>(ws, OFF_2A, 4, Ah, Al, G0, L);
    readS14(G0, L, qq);
    float vb2a = b2a[L];
#pragma unroll
    for (int k = 0; k < 14; ++k) pp[k] = pp[k] + vb2a - qq[k];
    // ---- L2b: H in G1, X out -> G0 ----
    {
        float bb[4];
#pragma unroll
        for (int nt = 0; nt < 4; ++nt) bb[nt] = b2b[nt * 16 + (L & 15)];
        edgeconv3(ws, OFF_2B, G1, G0, pp, qq, bb, L);
    }

    // ---- L3a (K=96): A from G0 + XS2, S in G1 ----
    loadA<3>(G0, XS2, L, Ah, Al);
    lin_pass<3, 8>(ws, OFF_3A, 0, Ah, Al, G1, L);
    readS14(G1, L, pp);
    lin_pass<3, 8>(ws, OFF_3A, 4, Ah, Al, G1, L);
    readS14(G1, L, qq);
    float vb3a = b3a[L];
#pragma unroll
    for (int k = 0; k < 14; ++k) pp[k] = pp[k] + vb3a - qq[k];

    // ---- L3b (64->3): H in G0, in-register max, direct global store ----
    {
        short8 B0h = *(const short8*)(ws + OFF_3B + L * 8);
        short8 B0l = *(const short8*)(ws + OFF_3B + 512 + L * 8);
        short8 B1h = *(const short8*)(ws + OFF_3B + 1024 + L * 8);
        short8 B1l = *(const short8*)(ws + OFF_3B + 1536 + L * 8);
        float t0 = tt[g0], t1 = tt[g0 + 1];   // std uses t[n // 7]
        float inv0 = 1.0f / (sqrtf((exp2f(t0 * 9.287712379549448f) - 1.0f) * 0.15533740282828987f) + 1e-7f);
        float inv1 = 1.0f / (sqrtf((exp2f(t1 * 9.287712379549448f) - 1.0f) * 0.15533740282828987f) + 1e-7f);
        float vb3b = b3b[(L & 15) < 3 ? (L & 15) : 0];
        int q = L >> 4;
#pragma unroll
        for (int c = 0; c < 7; ++c) {
            stageH2(G0, c, pp, qq, L);
            short8 Ah0, Ah1, Al0, Al1;
            loadAH(G0, L, Ah0, Ah1, Al0, Al1);
            f32x4 acc = {0.f, 0.f, 0.f, 0.f};
            acc = mfma3(Ah0, Al0, B0h, B0l, acc);
            acc = mfma3(Ah1, Al1, B1h, B1l, acc);
            float m = fmaxf(fmaxf(acc[0], acc[1]), fmaxf(acc[2], acc[3]));
            m = fmaxf(m, __shfl_xor(m, 16, 64));
            int gidx = c * 2 + (q >> 1);
            int gb = (gidx >= 7) ? 1 : 0;
            if ((L & 15) < 3 && !(q & 1)) {
                float v = (m + vb3b) * (gb ? inv1 : inv0);
                out[(base0 + gidx) * 3 + (L & 15)] = v;
            }
        }
    }
}

extern "C" void kernel_launch(void* const* d_in, const int* in_sizes, int n_in,
                              void* d_out, int out_size, void* d_ws, size_t ws_size,
                              hipStream_t stream) {
    const float* omega = (const float*)d_in[0];
    // d_in[1] edge_index unused (fixed fully-connected); d_in[3] num_objs == 7
    const float* tt  = (const float*)d_in[2];
    const float* Wf  = (const float*)d_in[4];
    const float* wi1 = (const float*)d_in[5];
    const float* bi1 = (const float*)d_in[6];
    const float* wi2 = (const float*)d_in[7];
    const float* bi2 = (const float*)d_in[8];
    const float* wt  = (const float*)d_in[9];
    const float* bt  = (const float*)d_in[10];
    const float* w1a = (const float*)d_in[11];
    const float* b1a = (const float*)d_in[12];
    const float* w1b = (const float*)d_in[13];
    const float* b1b = (const float*)d_in[14];
    const float* w2a = (const float*)d_in[15];
    const float* b2a = (const float*)d_in[16];
    const float* w2b = (const float*)d_in[17];
    const float* b2b = (const float*)d_in[18];
    const float* w3a = (const float*)d_in[19];
    const float* b3a = (const float*)d_in[20];
    const float* w3b = (const float*)d_in[21];
    const float* b3b = (const float*)d_in[22];
    u16* ws = (u16*)d_ws;   // needs 188416 bytes

    pack_kernel<<<dim3(92), dim3(128), 0, stream>>>(wi2, w1a, w2a, w3a, w1b, w2b, wt, w3b, ws);
    gnn_kernel<<<dim3(12500), dim3(128), 0, stream>>>(
        omega, tt, Wf, wi1, bi1, bi2, bt,
        b1a, b1b, b2a, b2b, b3a, b3b, ws, (float*)d_out);
}

// Round 11
// 451.889 us; speedup vs baseline: 1.2455x; 1.2455x over previous
//
#include <hip/hip_runtime.h>

// ScoreNetGNN: B=50000 graphs x 7 nodes, fully-connected (42 edges/graph).
// R6: MFMA pipeline (16x16x32 bf16 split hi+lo). R7: strides/LDS. R8: two
// graphs/wave. R9 (best 487us): 128-thr blocks, de-resident B, S-readback max.
// R10 in-register max REGRESSED (563) -> reverted.
// R11 = R9 + dependency-chain attack:
//  (1) two-chain MFMA accumulation (a1=ah*bh; a2=ah*bl+al*bh; sum at end):
//      critical path 3KT -> 2KT, 8 independent MFMA streams per lin_pass.
//  (2) software-pipelined edgeconv/L3b: double-buffered H (W/H1); stage chunk
//      c+1 writes + read chunk c-1 S-max during chunk c MFMAs; prefetch A-frags.
//  (3) __sinf/__cosf in temb (kills ~500 libm VALU instrs/pair).
// f32 I/O hardcoded (R3 counters: WRITE_SIZE = 4 B/elem).

#define NB 50000

typedef unsigned short u16;
typedef short short8 __attribute__((ext_vector_type(8)));
typedef float f32x4 __attribute__((ext_vector_type(4)));

// d_ws fragment offsets (u16 units). frag stride 1024 u16 (hi 512 | lo 512),
// lane entry = 8 u16 (16B). Total 94208 u16 = 188416 bytes.
#define OFF_I  0
#define OFF_1A 8192
#define OFF_2A 24576
#define OFF_3A 49152
#define OFF_1B 73728
#define OFF_2B 81920
#define OFF_WT 90112
#define OFF_3B 92160

// LDS per-wave geometry (bytes). W/H1: 16 rows x 64 bf16 @ stride 144
// (36 dw == 4 mod 32 -> worst 2-way, free), hi [0,2304) lo [2304,4608).
// XS2: xs strip 16 x 32 bf16 @ stride 72, write-once. Sb: f32 C @ stride 264.
#define HSTR 144
#define HLO  2304
#define XS2S 72
#define XS2LO 1152
#define SSTR 264
#define WREG 15744   // W 4608 + XS2 2304 + H1 4608 + Sb 4224

__device__ __forceinline__ float b2f(u16 u) {
    return __uint_as_float(((unsigned int)u) << 16);
}
__device__ __forceinline__ u16 f2b(float f) {
    unsigned int u = __float_as_uint(f);
    u += 0x7FFFu + ((u >> 16) & 1u);   // RNE
    return (u16)(u >> 16);
}
__device__ __forceinline__ float bcast(float v, int l) {
    return __uint_as_float(__builtin_amdgcn_readlane(__float_as_uint(v), l));
}

// ---- setup: pack weights into split-bf16 MFMA B-fragments ----
__global__ __launch_bounds__(128) void pack_kernel(
    const float* __restrict__ wi2, const float* __restrict__ w1a,
    const float* __restrict__ w2a, const float* __restrict__ w3a,
    const float* __restrict__ w1b, const float* __restrict__ w2b,
    const float* __restrict__ wt,  const float* __restrict__ w3b,
    u16* __restrict__ ws)
{
    int blk = blockIdx.x;
    int half = threadIdx.x >> 6;          // 0 = hi, 1 = lo
    int lane = threadIdx.x & 63;
    if (blk < 88) {
        const float* src; int NT, qoff, obase, frag;
        if (blk < 8)       { src = wi2; NT = 4; qoff = 0;  obase = OFF_I;  frag = blk;      }
        else if (blk < 24) { src = w1a; NT = 8; qoff = 64; obase = OFF_1A; frag = blk - 8;  }
        else if (blk < 48) { src = w2a; NT = 8; qoff = 96; obase = OFF_2A; frag = blk - 24; }
        else if (blk < 72) { src = w3a; NT = 8; qoff = 96; obase = OFF_3A; frag = blk - 48; }
        else if (blk < 80) { src = w1b; NT = 4; qoff = 0;  obase = OFF_1B; frag = blk - 72; }
        else               { src = w2b; NT = 4; qoff = 0;  obase = OFF_2B; frag = blk - 80; }
        int kt = frag / NT, nt = frag % NT;
        int k0 = kt * 32 + (lane >> 4) * 8;
        int n  = nt * 16 + (lane & 15);
        u16* dst = ws + obase + frag * 1024 + half * 512 + lane * 8;
#pragma unroll
        for (int j = 0; j < 8; ++j) {
            int k = k0 + j;
            int idx = (n < 64) ? (k * 64 + n) : ((qoff + k) * 64 + (n - 64));
            float v = src[idx];
            u16 hi = f2b(v);
            dst[j] = (half == 0) ? hi : f2b(v - b2f(hi));
        }
    } else if (blk < 90) {               // wt (32,32): 2 n-frags
        int frag = blk - 88;
        int k0 = (lane >> 4) * 8;
        int n  = frag * 16 + (lane & 15);
        u16* dst = ws + OFF_WT + frag * 1024 + half * 512 + lane * 8;
#pragma unroll
        for (int j = 0; j < 8; ++j) {
            float v = wt[(k0 + j) * 32 + n];
            u16 hi = f2b(v);
            dst[j] = (half == 0) ? hi : f2b(v - b2f(hi));
        }
    } else {                             // w3b (64,3): 2 k-frags, cols 3..15 = 0
        int frag = blk - 90;
        int k0 = frag * 32 + (lane >> 4) * 8;
        int n  = lane & 15;
        u16* dst = ws + OFF_3B + frag * 1024 + half * 512 + lane * 8;
#pragma unroll
        for (int j = 0; j < 8; ++j) {
            float v = (n < 3) ? w3b[(k0 + j) * 3 + n] : 0.f;
            u16 hi = f2b(v);
            dst[j] = (half == 0) ? hi : f2b(v - b2f(hi));
        }
    }
}

__device__ __forceinline__ f32x4 mfma1(short8 a, short8 b, f32x4 acc) {
    return __builtin_amdgcn_mfma_f32_16x16x32_bf16(a, b, acc, 0, 0, 0);
}
__device__ __forceinline__ f32x4 mfma3(short8 ah, short8 al, short8 bh, short8 bl, f32x4 acc) {
    acc = mfma1(ah, bh, acc);
    acc = mfma1(ah, bl, acc);
    acc = mfma1(al, bh, acc);
    return acc;   // lo*lo dropped (~2^-18 rel)
}

// node k (0..13) -> row (g0 rows 0-6, g1 rows 8-14; rows 7,15 stale/unread)
#define ROW(k) ((k) < 7 ? (k) : (k) + 1)

// write 14 node values (64 cols) into region G as X
__device__ __forceinline__ void writeX64_14(char* G, int L, const float* v) {
#pragma unroll
    for (int k = 0; k < 14; ++k) {
        int r = ROW(k);
        u16 hi = f2b(v[k]);
        *(u16*)(G + r * HSTR + L * 2) = hi;
        *(u16*)(G + HLO + r * HSTR + L * 2) = f2b(v[k] - b2f(hi));
    }
}
// A-frags: kt 0,1 from G (cols 0-63); kt 2 from XS2 strip (cols 64-95)
template<int KT>
__device__ __forceinline__ void loadA(const char* G, const char* XS2, int L,
                                      short8* Ah, short8* Al) {
#pragma unroll
    for (int kt = 0; kt < KT; ++kt) {
        if (kt < 2) {
            Ah[kt] = *(const short8*)(G + (L & 15) * HSTR + kt * 64 + (L >> 4) * 16);
            Al[kt] = *(const short8*)(G + HLO + (L & 15) * HSTR + kt * 64 + (L >> 4) * 16);
        } else {
            Ah[kt] = *(const short8*)(XS2 + (L & 15) * XS2S + (L >> 4) * 16);
            Al[kt] = *(const short8*)(XS2 + XS2LO + (L & 15) * XS2S + (L >> 4) * 16);
        }
    }
}
// One 4-N-tile GEMM pass: S[row][col 0..63] = A(16xK) @ B(Kx64).
// Two independent accumulator chains per nt-tile (shorter MFMA critical path).
template<int KT, int NT>
__device__ __forceinline__ void lin_pass(const u16* __restrict__ ws, int off, int nt0,
                                         const short8* Ah, const short8* Al,
                                         char* Sg, int L) {
#pragma unroll
    for (int ntc = 0; ntc < 4; ++ntc) {
        f32x4 a1 = {0.f, 0.f, 0.f, 0.f}, a2 = {0.f, 0.f, 0.f, 0.f};
#pragma unroll
        for (int kt = 0; kt < KT; ++kt) {
            int f = kt * NT + nt0 + ntc;
            short8 bh = *(const short8*)(ws + off + f * 1024 + L * 8);
            short8 bl = *(const short8*)(ws + off + f * 1024 + 512 + L * 8);
            a1 = mfma1(Ah[kt], bh, a1);
            a2 = mfma1(Ah[kt], bl, a2);
            a2 = mfma1(Al[kt], bh, a2);
        }
#pragma unroll
        for (int rr = 0; rr < 4; ++rr)   // C: row=(L>>4)*4+rr, col=ntc*16+(L&15)
            *(float*)(Sg + ((L >> 4) * 4 + rr) * SSTR + ntc * 64 + (L & 15) * 4) = a1[rr] + a2[rr];
    }
}
__device__ __forceinline__ void readS14(const char* Sg, int L, float* o) {
#pragma unroll
    for (int k = 0; k < 14; ++k) o[k] = *(const float*)(Sg + ROW(k) * SSTR + L * 4);
}
// stage 16 edge rows (chunk c of 6; 84 real edges) of hv = relu(pp_i + qq_j)
__device__ __forceinline__ void stageH2(char* G, int c, const float* pp, const float* qq, int L) {
#pragma unroll
    for (int r = 0; r < 16; ++r) {
        int e = c * 16 + r;
        if (e < 84) {
            int gb = (e >= 42) ? 1 : 0;
            int el = e - gb * 42;
            int i = el / 6, jj = el - i * 6;
            int j = jj + (jj >= i);
            float hv = fmaxf(pp[gb * 7 + i] + qq[gb * 7 + j], 0.f);
            u16 hi = f2b(hv);
            *(u16*)(G + r * HSTR + L * 2) = hi;
            *(u16*)(G + HLO + r * HSTR + L * 2) = f2b(hv - b2f(hi));
        }
    }
}
__device__ __forceinline__ void loadAH(const char* G, int L,
                                       short8& Ah0, short8& Ah1, short8& Al0, short8& Al1) {
    Ah0 = *(const short8*)(G + (L & 15) * HSTR + (L >> 4) * 16);
    Ah1 = *(const short8*)(G + (L & 15) * HSTR + 64 + (L >> 4) * 16);
    Al0 = *(const short8*)(G + HLO + (L & 15) * HSTR + (L >> 4) * 16);
    Al1 = *(const short8*)(G + HLO + (L & 15) * HSTR + 64 + (L >> 4) * 16);
}
// fold chunk cc's S rows into per-node running max (column L)
__device__ __forceinline__ void maxread(const char* Sb, int cc, float* mx, int L) {
#pragma unroll
    for (int r = 0; r < 16; ++r) {
        int e = cc * 16 + r;
        if (e < 84) {
            int gb = (e >= 42) ? 1 : 0;
            int i = (e - gb * 42) / 6;
            float sv = *(const float*)(Sb + r * SSTR + L * 4);
            mx[gb * 7 + i] = fmaxf(mx[gb * 7 + i], sv);
        }
    }
}

// EdgeConv second linear (64->64) + max-agg + bias + relu via MFMA,
// software-pipelined across 6 chunks with double-buffered H (W / H1):
// stage c+1 and fold c-1 while chunk c's MFMAs run; prefetch c+1 A-frags.
// Output X written back into W.
__device__ __forceinline__ void edgeconv_pipe(const u16* __restrict__ ws, int offB,
                                              char* W, char* H1, char* Sb,
                                              const float* pp, const float* qq,
                                              float vb, int L) {
    float mx[14];
#pragma unroll
    for (int k = 0; k < 14; ++k) mx[k] = -3.0e38f;
    stageH2(W, 0, pp, qq, L);
    short8 Ah0, Ah1, Al0, Al1;
    loadAH(W, L, Ah0, Ah1, Al0, Al1);
#pragma unroll
    for (int c = 0; c < 6; ++c) {
        char* Hn = ((c + 1) & 1) ? H1 : W;
        if (c < 5) stageH2(Hn, c + 1, pp, qq, L);   // overlaps chunk-c MFMAs
        if (c > 0) maxread(Sb, c - 1, mx, L);       // before S is overwritten
#pragma unroll
        for (int nt = 0; nt < 4; ++nt) {
            short8 bh0 = *(const short8*)(ws + offB + nt * 1024 + L * 8);
            short8 bl0 = *(const short8*)(ws + offB + nt * 1024 + 512 + L * 8);
            short8 bh1 = *(const short8*)(ws + offB + (4 + nt) * 1024 + L * 8);
            short8 bl1 = *(const short8*)(ws + offB + (4 + nt) * 1024 + 512 + L * 8);
            f32x4 a1 = {0.f, 0.f, 0.f, 0.f}, a2 = {0.f, 0.f, 0.f, 0.f};
            a1 = mfma1(Ah0, bh0, a1);
            a2 = mfma1(Ah0, bl0, a2);
            a2 = mfma1(Al0, bh0, a2);
            a1 = mfma1(Ah1, bh1, a1);
            a2 = mfma1(Ah1, bl1, a2);
            a2 = mfma1(Al1, bh1, a2);
#pragma unroll
            for (int rr = 0; rr < 4; ++rr)
                *(float*)(Sb + ((L >> 4) * 4 + rr) * SSTR + nt * 64 + (L & 15) * 4) = a1[rr] + a2[rr];
        }
        if (c < 5) loadAH(Hn, L, Ah0, Ah1, Al0, Al1);   // prefetch next chunk
    }
    maxread(Sb, 5, mx, L);
    float xo[14];
#pragma unroll
    for (int k = 0; k < 14; ++k) xo[k] = fmaxf(mx[k] + vb, 0.f);
    writeX64_14(W, L, xo);
}

__global__ __launch_bounds__(128) void gnn_kernel(
    const float* __restrict__ omega, const float* __restrict__ tt, const float* __restrict__ Wf,
    const float* __restrict__ wi1, const float* __restrict__ bi1, const float* __restrict__ bi2,
    const float* __restrict__ bt,
    const float* __restrict__ b1a, const float* __restrict__ b1b,
    const float* __restrict__ b2a, const float* __restrict__ b2b,
    const float* __restrict__ b3a, const float* __restrict__ b3b,
    const u16* __restrict__ ws, float* __restrict__ out)
{
    __shared__ __align__(16) char smem[2 * WREG];   // 31488 B/block
    const int L   = threadIdx.x & 63;
    const int wav = threadIdx.x >> 6;
    const int p   = blockIdx.x * 2 + wav;    // graph pair id, grid covers 25000
    const int g0  = p * 2;
    const int base0 = g0 * 7;                // g1 nodes start at base0+7
    char* W   = smem + wav * WREG;
    char* XS2 = W + 4608;
    char* H1  = W + 6912;
    char* Sb  = W + 11520;

    // ---- h1 = relu(omega@wi1 + bi1), both graphs (42 contiguous coords) ----
    float omv = (L < 42) ? omega[base0 * 3 + L] : 0.f;
    float vwi10 = wi1[L], vwi11 = wi1[64 + L], vwi12 = wi1[128 + L];
    float vbi1 = bi1[L];
    float h1[14];
#pragma unroll
    for (int k = 0; k < 14; ++k) {
        float a0 = bcast(omv, 3 * k), a1 = bcast(omv, 3 * k + 1), a2 = bcast(omv, 3 * k + 2);
        h1[k] = fmaxf(fmaf(a0, vwi10, fmaf(a1, vwi11, fmaf(a2, vwi12, vbi1))), 0.f);
    }

    // ---- time embedding via MFMA (tile-bug: node n uses t[n % B]) ----
    // E staged in W (cols 0-31); C -> Sb; xs written ONCE to XS2.
    {
        int cc = L & 31;
        float vwf = Wf[cc & 15] * 6.283185307179586f;
        int tb = base0 - (base0 / NB) * NB;        // base0 % NB
#pragma unroll
        for (int k = 0; k < 14; ++k) {
            int ti = tb + k; if (ti >= NB) ti -= NB;
            float pj = tt[ti] * vwf;
            float remb = fmaxf((cc < 16) ? __sinf(pj) : __cosf(pj), 0.f);
            u16 hi = f2b(remb);
            if (L < 32) *(u16*)(W + ROW(k) * HSTR + cc * 2) = hi;
            else *(u16*)(W + HLO + ROW(k) * HSTR + cc * 2) = f2b(remb - b2f(hi));
        }
        short8 Eh = *(const short8*)(W + (L & 15) * HSTR + (L >> 4) * 16);
        short8 El = *(const short8*)(W + HLO + (L & 15) * HSTR + (L >> 4) * 16);
#pragma unroll
        for (int nt = 0; nt < 2; ++nt) {
            short8 bh = *(const short8*)(ws + OFF_WT + nt * 1024 + L * 8);
            short8 bl = *(const short8*)(ws + OFF_WT + nt * 1024 + 512 + L * 8);
            f32x4 acc = {0.f, 0.f, 0.f, 0.f};
            acc = mfma3(Eh, El, bh, bl, acc);
#pragma unroll
            for (int rr = 0; rr < 4; ++rr)
                *(float*)(Sb + ((L >> 4) * 4 + rr) * SSTR + nt * 64 + (L & 15) * 4) = acc[rr];
        }
        float vbt = bt[cc];
#pragma unroll
        for (int k = 0; k < 14; ++k) {
            float xv = fmaxf(*(const float*)(Sb + ROW(k) * SSTR + cc * 4) + vbt, 0.f);
            u16 hi = f2b(xv);
            if (L < 32) *(u16*)(XS2 + ROW(k) * XS2S + cc * 2) = hi;
            else *(u16*)(XS2 + XS2LO + ROW(k) * XS2S + cc * 2) = f2b(xv - b2f(hi));
        }
    }

    short8 Ah[3], Al[3];
    float pp[14], qq[14];

    // ---- init: x0 = h1 @ wi2 + bi2  (X: W, S: Sb, X back to W) ----
    writeX64_14(W, L, h1);
    loadA<2>(W, XS2, L, Ah, Al);
    lin_pass<2, 4>(ws, OFF_I, 0, Ah, Al, Sb, L);
    {
        float xh[14];
        readS14(Sb, L, xh);
        float vbi2 = bi2[L];
#pragma unroll
        for (int k = 0; k < 14; ++k) xh[k] += vbi2;
        writeX64_14(W, L, xh);
    }

    // ---- L1a (K=64): A from W, S in Sb ----
    loadA<2>(W, XS2, L, Ah, Al);
    lin_pass<2, 8>(ws, OFF_1A, 0, Ah, Al, Sb, L);
    readS14(Sb, L, pp);
    lin_pass<2, 8>(ws, OFF_1A, 4, Ah, Al, Sb, L);
    readS14(Sb, L, qq);
    float vb1a = b1a[L];
#pragma unroll
    for (int k = 0; k < 14; ++k) pp[k] = pp[k] + vb1a - qq[k];
    // ---- L1b (pipelined; X out -> W) ----
    edgeconv_pipe(ws, OFF_1B, W, H1, Sb, pp, qq, b1b[L], L);

    // ---- L2a (K=96: [x | xs]) ----
    loadA<3>(W, XS2, L, Ah, Al);
    lin_pass<3, 8>(ws, OFF_2A, 0, Ah, Al, Sb, L);
    readS14(Sb, L, pp);
    lin_pass<3, 8>(ws, OFF_2A, 4, Ah, Al, Sb, L);
    readS14(Sb, L, qq);
    float vb2a = b2a[L];
#pragma unroll
    for (int k = 0; k < 14; ++k) pp[k] = pp[k] + vb2a - qq[k];
    // ---- L2b ----
    edgeconv_pipe(ws, OFF_2B, W, H1, Sb, pp, qq, b2b[L], L);

    // ---- L3a (K=96) ----
    loadA<3>(W, XS2, L, Ah, Al);
    lin_pass<3, 8>(ws, OFF_3A, 0, Ah, Al, Sb, L);
    readS14(Sb, L, pp);
    lin_pass<3, 8>(ws, OFF_3A, 4, Ah, Al, Sb, L);
    readS14(Sb, L, qq);
    float vb3a = b3a[L];
#pragma unroll
    for (int k = 0; k < 14; ++k) pp[k] = pp[k] + vb3a - qq[k];

    // ---- L3b (64->3) via MFMA (pipelined) + max + /(std+1e-7) ----
    {
        short8 B0h = *(const short8*)(ws + OFF_3B + L * 8);
        short8 B0l = *(const short8*)(ws + OFF_3B + 512 + L * 8);
        short8 B1h = *(const short8*)(ws + OFF_3B + 1024 + L * 8);
        short8 B1l = *(const short8*)(ws + OFF_3B + 1536 + L * 8);
        stageH2(W, 0, pp, qq, L);
        short8 Ah0, Ah1, Al0, Al1;
        loadAH(W, L, Ah0, Ah1, Al0, Al1);
#pragma unroll
        for (int c = 0; c < 6; ++c) {
            char* Hn = ((c + 1) & 1) ? H1 : W;
            if (c < 5) stageH2(Hn, c + 1, pp, qq, L);
            f32x4 a1 = {0.f, 0.f, 0.f, 0.f}, a2 = {0.f, 0.f, 0.f, 0.f};
            a1 = mfma1(Ah0, B0h, a1);
            a2 = mfma1(Ah0, B0l, a2);
            a2 = mfma1(Al0, B0h, a2);
            a1 = mfma1(Ah1, B1h, a1);
            a2 = mfma1(Ah1, B1l, a2);
            a2 = mfma1(Al1, B1h, a2);
            if ((L & 15) < 3) {       // compact strip: row e (96), stride 16B, col 0..2
#pragma unroll
                for (int rr = 0; rr < 4; ++rr)
                    *(float*)(Sb + (c * 16 + (L >> 4) * 4 + rr) * 16 + (L & 15) * 4) = a1[rr] + a2[rr];
            }
            if (c < 5) loadAH(Hn, L, Ah0, Ah1, Al0, Al1);
        }
        if (L < 42) {                 // lanes 0-20: g0; 21-41: g1
            int gb = (L >= 21) ? 1 : 0;
            int ll = L - gb * 21;
            int i = ll / 3, col = ll - i * 3;
            int e0 = gb * 42 + i * 6;
            float m = -3.0e38f;
#pragma unroll
            for (int e6 = 0; e6 < 6; ++e6)
                m = fmaxf(m, *(const float*)(Sb + (e0 + e6) * 16 + col * 4));
            m += b3b[col];
            float tg = tt[g0 + gb];   // std uses t[n // 7]
            float stdv = sqrtf((exp2f(tg * 9.287712379549448f) - 1.0f) * 0.15533740282828987f);
            out[base0 * 3 + L] = m / (stdv + 1e-7f);   // contiguous 42 outputs
        }
    }
}

extern "C" void kernel_launch(void* const* d_in, const int* in_sizes, int n_in,
                              void* d_out, int out_size, void* d_ws, size_t ws_size,
                              hipStream_t stream) {
    const float* omega = (const float*)d_in[0];
    // d_in[1] edge_index unused (fixed fully-connected); d_in[3] num_objs == 7
    const float* tt  = (const float*)d_in[2];
    const float* Wf  = (const float*)d_in[4];
    const float* wi1 = (const float*)d_in[5];
    const float* bi1 = (const float*)d_in[6];
    const float* wi2 = (const float*)d_in[7];
    const float* bi2 = (const float*)d_in[8];
    const float* wt  = (const float*)d_in[9];
    const float* bt  = (const float*)d_in[10];
    const float* w1a = (const float*)d_in[11];
    const float* b1a = (const float*)d_in[12];
    const float* w1b = (const float*)d_in[13];
    const float* b1b = (const float*)d_in[14];
    const float* w2a = (const float*)d_in[15];
    const float* b2a = (const float*)d_in[16];
    const float* w2b = (const float*)d_in[17];
    const float* b2b = (const float*)d_in[18];
    const float* w3a = (const float*)d_in[19];
    const float* b3a = (const float*)d_in[20];
    const float* w3b = (const float*)d_in[21];
    const float* b3b = (const float*)d_in[22];
    u16* ws = (u16*)d_ws;   // needs 188416 bytes

    pack_kernel<<<dim3(92), dim3(128), 0, stream>>>(wi2, w1a, w2a, w3a, w1b, w2b, wt, w3b, ws);
    gnn_kernel<<<dim3(12500), dim3(128), 0, stream>>>(
        omega, tt, Wf, wi1, bi1, bi2, bt,
        b1a, b1b, b2a, b2b, b3a, b3b, ws, (float*)d_out);
}

// Round 12
// 425.029 us; speedup vs baseline: 1.3242x; 1.0632x over previous
//
#include <hip/hip_runtime.h>

// ScoreNetGNN: B=50000 graphs x 7 nodes, fully-connected (42 edges/graph).
// R6: MFMA pipeline (16x16x32 bf16 split hi+lo). R7: strides/LDS. R8: two
// graphs/wave. R9: 128-thr blocks. R11 (best, 452us): two-chain MFMA accum,
// software-pipelined edgeconv, __sinf. R12: VALU diet —
//  (1) truncation-split: hi = top16(v) (v - hi exact, Sterbenz), lo = RNE(v-hi):
//      12 -> 8 VALU per staged element (~370 elems/pair);
//  (2) edgeconv B-frags resident in regs again (R8-style): 192 -> 32 global
//      b128/pair; VGPRs are free since occupancy pins at 2 waves/SIMD.
// f32 I/O hardcoded (R3 counters: WRITE_SIZE = 4 B/elem).

#define NB 50000

typedef unsigned short u16;
typedef short short8 __attribute__((ext_vector_type(8)));
typedef float f32x4 __attribute__((ext_vector_type(4)));

// d_ws fragment offsets (u16 units). frag stride 1024 u16 (hi 512 | lo 512),
// lane entry = 8 u16 (16B). Total 94208 u16 = 188416 bytes.
#define OFF_I  0
#define OFF_1A 8192
#define OFF_2A 24576
#define OFF_3A 49152
#define OFF_1B 73728
#define OFF_2B 81920
#define OFF_WT 90112
#define OFF_3B 92160

// LDS per-wave geometry (bytes). W/H1: 16 rows x 64 bf16 @ stride 144
// (36 dw == 4 mod 32 -> worst 2-way, free), hi [0,2304) lo [2304,4608).
// XS2: xs strip 16 x 32 bf16 @ stride 72, write-once. Sb: f32 C @ stride 264.
#define HSTR 144
#define HLO  2304
#define XS2S 72
#define XS2LO 1152
#define SSTR 264
#define WREG 15744   // W 4608 + XS2 2304 + H1 4608 + Sb 4224

__device__ __forceinline__ float b2f(u16 u) {
    return __uint_as_float(((unsigned int)u) << 16);
}
__device__ __forceinline__ u16 f2b(float f) {
    unsigned int u = __float_as_uint(f);
    u += 0x7FFFu + ((u >> 16) & 1u);   // RNE
    return (u16)(u >> 16);
}
// split v into bf16 hi (truncated, v-hi exact) + bf16 lo (RNE of residual):
// error <= 2^-17 |v|; 8 VALU vs 12 for double-RNE.
__device__ __forceinline__ void split2(float v, u16& h, u16& l) {
    unsigned int u = __float_as_uint(v);
    h = (u16)(u >> 16);
    float d = v - __uint_as_float(u & 0xffff0000u);
    l = f2b(d);
}
__device__ __forceinline__ float bcast(float v, int l) {
    return __uint_as_float(__builtin_amdgcn_readlane(__float_as_uint(v), l));
}

// ---- setup: pack weights into split-bf16 MFMA B-fragments (RNE hi: runs once) ----
__global__ __launch_bounds__(128) void pack_kernel(
    const float* __restrict__ wi2, const float* __restrict__ w1a,
    const float* __restrict__ w2a, const float* __restrict__ w3a,
    const float* __restrict__ w1b, const float* __restrict__ w2b,
    const float* __restrict__ wt,  const float* __restrict__ w3b,
    u16* __restrict__ ws)
{
    int blk = blockIdx.x;
    int half = threadIdx.x >> 6;          // 0 = hi, 1 = lo
    int lane = threadIdx.x & 63;
    if (blk < 88) {
        const float* src; int NT, qoff, obase, frag;
        if (blk < 8)       { src = wi2; NT = 4; qoff = 0;  obase = OFF_I;  frag = blk;      }
        else if (blk < 24) { src = w1a; NT = 8; qoff = 64; obase = OFF_1A; frag = blk - 8;  }
        else if (blk < 48) { src = w2a; NT = 8; qoff = 96; obase = OFF_2A; frag = blk - 24; }
        else if (blk < 72) { src = w3a; NT = 8; qoff = 96; obase = OFF_3A; frag = blk - 48; }
        else if (blk < 80) { src = w1b; NT = 4; qoff = 0;  obase = OFF_1B; frag = blk - 72; }
        else               { src = w2b; NT = 4; qoff = 0;  obase = OFF_2B; frag = blk - 80; }
        int kt = frag / NT, nt = frag % NT;
        int k0 = kt * 32 + (lane >> 4) * 8;
        int n  = nt * 16 + (lane & 15);
        u16* dst = ws + obase + frag * 1024 + half * 512 + lane * 8;
#pragma unroll
        for (int j = 0; j < 8; ++j) {
            int k = k0 + j;
            int idx = (n < 64) ? (k * 64 + n) : ((qoff + k) * 64 + (n - 64));
            float v = src[idx];
            u16 hi = f2b(v);
            dst[j] = (half == 0) ? hi : f2b(v - b2f(hi));
        }
    } else if (blk < 90) {               // wt (32,32): 2 n-frags
        int frag = blk - 88;
        int k0 = (lane >> 4) * 8;
        int n  = frag * 16 + (lane & 15);
        u16* dst = ws + OFF_WT + frag * 1024 + half * 512 + lane * 8;
#pragma unroll
        for (int j = 0; j < 8; ++j) {
            float v = wt[(k0 + j) * 32 + n];
            u16 hi = f2b(v);
            dst[j] = (half == 0) ? hi : f2b(v - b2f(hi));
        }
    } else {                             // w3b (64,3): 2 k-frags, cols 3..15 = 0
        int frag = blk - 90;
        int k0 = frag * 32 + (lane >> 4) * 8;
        int n  = lane & 15;
        u16* dst = ws + OFF_3B + frag * 1024 + half * 512 + lane * 8;
#pragma unroll
        for (int j = 0; j < 8; ++j) {
            float v = (n < 3) ? w3b[(k0 + j) * 3 + n] : 0.f;
            u16 hi = f2b(v);
            dst[j] = (half == 0) ? hi : f2b(v - b2f(hi));
        }
    }
}

__device__ __forceinline__ f32x4 mfma1(short8 a, short8 b, f32x4 acc) {
    return __builtin_amdgcn_mfma_f32_16x16x32_bf16(a, b, acc, 0, 0, 0);
}
__device__ __forceinline__ f32x4 mfma3(short8 ah, short8 al, short8 bh, short8 bl, f32x4 acc) {
    acc = mfma1(ah, bh, acc);
    acc = mfma1(ah, bl, acc);
    acc = mfma1(al, bh, acc);
    return acc;   // lo*lo dropped
}

// node k (0..13) -> row (g0 rows 0-6, g1 rows 8-14; rows 7,15 stale/unread)
#define ROW(k) ((k) < 7 ? (k) : (k) + 1)

// write 14 node values (64 cols) into region G as X
__device__ __forceinline__ void writeX64_14(char* G, int L, const float* v) {
#pragma unroll
    for (int k = 0; k < 14; ++k) {
        int r = ROW(k);
        u16 h, l;
        split2(v[k], h, l);
        *(u16*)(G + r * HSTR + L * 2) = h;
        *(u16*)(G + HLO + r * HSTR + L * 2) = l;
    }
}
// A-frags: kt 0,1 from G (cols 0-63); kt 2 from XS2 strip (cols 64-95)
template<int KT>
__device__ __forceinline__ void loadA(const char* G, const char* XS2, int L,
                                      short8* Ah, short8* Al) {
#pragma unroll
    for (int kt = 0; kt < KT; ++kt) {
        if (kt < 2) {
            Ah[kt] = *(const short8*)(G + (L & 15) * HSTR + kt * 64 + (L >> 4) * 16);
            Al[kt] = *(const short8*)(G + HLO + (L & 15) * HSTR + kt * 64 + (L >> 4) * 16);
        } else {
            Ah[kt] = *(const short8*)(XS2 + (L & 15) * XS2S + (L >> 4) * 16);
            Al[kt] = *(const short8*)(XS2 + XS2LO + (L & 15) * XS2S + (L >> 4) * 16);
        }
    }
}
// One 4-N-tile GEMM pass: S[row][col 0..63] = A(16xK) @ B(Kx64).
// Two independent accumulator chains per nt-tile.
template<int KT, int NT>
__device__ __forceinline__ void lin_pass(const u16* __restrict__ ws, int off, int nt0,
                                         const short8* Ah, const short8* Al,
                                         char* Sg, int L) {
#pragma unroll
    for (int ntc = 0; ntc < 4; ++ntc) {
        f32x4 a1 = {0.f, 0.f, 0.f, 0.f}, a2 = {0.f, 0.f, 0.f, 0.f};
#pragma unroll
        for (int kt = 0; kt < KT; ++kt) {
            int f = kt * NT + nt0 + ntc;
            short8 bh = *(const short8*)(ws + off + f * 1024 + L * 8);
            short8 bl = *(const short8*)(ws + off + f * 1024 + 512 + L * 8);
            a1 = mfma1(Ah[kt], bh, a1);
            a2 = mfma1(Ah[kt], bl, a2);
            a2 = mfma1(Al[kt], bh, a2);
        }
#pragma unroll
        for (int rr = 0; rr < 4; ++rr)   // C: row=(L>>4)*4+rr, col=ntc*16+(L&15)
            *(float*)(Sg + ((L >> 4) * 4 + rr) * SSTR + ntc * 64 + (L & 15) * 4) = a1[rr] + a2[rr];
    }
}
__device__ __forceinline__ void readS14(const char* Sg, int L, float* o) {
#pragma unroll
    for (int k = 0; k < 14; ++k) o[k] = *(const float*)(Sg + ROW(k) * SSTR + L * 4);
}
// stage 16 edge rows (chunk c of 6; 84 real edges) of hv = relu(pp_i + qq_j)
__device__ __forceinline__ void stageH2(char* G, int c, const float* pp, const float* qq, int L) {
#pragma unroll
    for (int r = 0; r < 16; ++r) {
        int e = c * 16 + r;
        if (e < 84) {
            int gb = (e >= 42) ? 1 : 0;
            int el = e - gb * 42;
            int i = el / 6, jj = el - i * 6;
            int j = jj + (jj >= i);
            float hv = fmaxf(pp[gb * 7 + i] + qq[gb * 7 + j], 0.f);
            u16 h, l;
            split2(hv, h, l);
            *(u16*)(G + r * HSTR + L * 2) = h;
            *(u16*)(G + HLO + r * HSTR + L * 2) = l;
        }
    }
}
__device__ __forceinline__ void loadAH(const char* G, int L,
                                       short8& Ah0, short8& Ah1, short8& Al0, short8& Al1) {
    Ah0 = *(const short8*)(G + (L & 15) * HSTR + (L >> 4) * 16);
    Ah1 = *(const short8*)(G + (L & 15) * HSTR + 64 + (L >> 4) * 16);
    Al0 = *(const short8*)(G + HLO + (L & 15) * HSTR + (L >> 4) * 16);
    Al1 = *(const short8*)(G + HLO + (L & 15) * HSTR + 64 + (L >> 4) * 16);
}
// fold chunk cc's S rows into per-node running max (column L)
__device__ __forceinline__ void maxread(const char* Sb, int cc, float* mx, int L) {
#pragma unroll
    for (int r = 0; r < 16; ++r) {
        int e = cc * 16 + r;
        if (e < 84) {
            int gb = (e >= 42) ? 1 : 0;
            int i = (e - gb * 42) / 6;
            float sv = *(const float*)(Sb + r * SSTR + L * 4);
            mx[gb * 7 + i] = fmaxf(mx[gb * 7 + i], sv);
        }
    }
}

// EdgeConv second linear (64->64) + max-agg + bias + relu via MFMA,
// software-pipelined across 6 chunks with double-buffered H (W / H1).
// B-frags resident in registers (reused 6x). Output X written back into W.
__device__ __forceinline__ void edgeconv_pipe(const u16* __restrict__ ws, int offB,
                                              char* W, char* H1, char* Sb,
                                              const float* pp, const float* qq,
                                              float vb, int L) {
    short8 Bh[8], Bl[8];            // f = kt*4+nt, resident across all 6 chunks
#pragma unroll
    for (int f = 0; f < 8; ++f) {
        Bh[f] = *(const short8*)(ws + offB + f * 1024 + L * 8);
        Bl[f] = *(const short8*)(ws + offB + f * 1024 + 512 + L * 8);
    }
    float mx[14];
#pragma unroll
    for (int k = 0; k < 14; ++k) mx[k] = -3.0e38f;
    stageH2(W, 0, pp, qq, L);
    short8 Ah0, Ah1, Al0, Al1;
    loadAH(W, L, Ah0, Ah1, Al0, Al1);
#pragma unroll
    for (int c = 0; c < 6; ++c) {
        char* Hn = ((c + 1) & 1) ? H1 : W;
        if (c < 5) stageH2(Hn, c + 1, pp, qq, L);   // overlaps chunk-c MFMAs
        if (c > 0) maxread(Sb, c - 1, mx, L);       // before S is overwritten
#pragma unroll
        for (int nt = 0; nt < 4; ++nt) {
            f32x4 a1 = {0.f, 0.f, 0.f, 0.f}, a2 = {0.f, 0.f, 0.f, 0.f};
            a1 = mfma1(Ah0, Bh[nt], a1);
            a2 = mfma1(Ah0, Bl[nt], a2);
            a2 = mfma1(Al0, Bh[nt], a2);
            a1 = mfma1(Ah1, Bh[4 + nt], a1);
            a2 = mfma1(Ah1, Bl[4 + nt], a2);
            a2 = mfma1(Al1, Bh[4 + nt], a2);
#pragma unroll
            for (int rr = 0; rr < 4; ++rr)
                *(float*)(Sb + ((L >> 4) * 4 + rr) * SSTR + nt * 64 + (L & 15) * 4) = a1[rr] + a2[rr];
        }
        if (c < 5) loadAH(Hn, L, Ah0, Ah1, Al0, Al1);   // prefetch next chunk
    }
    maxread(Sb, 5, mx, L);
    float xo[14];
#pragma unroll
    for (int k = 0; k < 14; ++k) xo[k] = fmaxf(mx[k] + vb, 0.f);
    writeX64_14(W, L, xo);
}

__global__ __launch_bounds__(128) void gnn_kernel(
    const float* __restrict__ omega, const float* __restrict__ tt, const float* __restrict__ Wf,
    const float* __restrict__ wi1, const float* __restrict__ bi1, const float* __restrict__ bi2,
    const float* __restrict__ bt,
    const float* __restrict__ b1a, const float* __restrict__ b1b,
    const float* __restrict__ b2a, const float* __restrict__ b2b,
    const float* __restrict__ b3a, const float* __restrict__ b3b,
    const u16* __restrict__ ws, float* __restrict__ out)
{
    __shared__ __align__(16) char smem[2 * WREG];   // 31488 B/block
    const int L   = threadIdx.x & 63;
    const int wav = threadIdx.x >> 6;
    const int p   = blockIdx.x * 2 + wav;    // graph pair id, grid covers 25000
    const int g0  = p * 2;
    const int base0 = g0 * 7;                // g1 nodes start at base0+7
    char* W   = smem + wav * WREG;
    char* XS2 = W + 4608;
    char* H1  = W + 6912;
    char* Sb  = W + 11520;

    // ---- h1 = relu(omega@wi1 + bi1), both graphs (42 contiguous coords) ----
    float omv = (L < 42) ? omega[base0 * 3 + L] : 0.f;
    float vwi10 = wi1[L], vwi11 = wi1[64 + L], vwi12 = wi1[128 + L];
    float vbi1 = bi1[L];
    float h1[14];
#pragma unroll
    for (int k = 0; k < 14; ++k) {
        float a0 = bcast(omv, 3 * k), a1 = bcast(omv, 3 * k + 1), a2 = bcast(omv, 3 * k + 2);
        h1[k] = fmaxf(fmaf(a0, vwi10, fmaf(a1, vwi11, fmaf(a2, vwi12, vbi1))), 0.f);
    }

    // ---- time embedding via MFMA (tile-bug: node n uses t[n % B]) ----
    // E staged in W (cols 0-31); C -> Sb; xs written ONCE to XS2.
    {
        int cc = L & 31;
        float vwf = Wf[cc & 15] * 6.283185307179586f;
        int tb = base0 - (base0 / NB) * NB;        // base0 % NB
#pragma unroll
        for (int k = 0; k < 14; ++k) {
            int ti = tb + k; if (ti >= NB) ti -= NB;
            float pj = tt[ti] * vwf;
            float remb = fmaxf((cc < 16) ? __sinf(pj) : __cosf(pj), 0.f);
            u16 h, l;
            split2(remb, h, l);
            if (L < 32) *(u16*)(W + ROW(k) * HSTR + cc * 2) = h;
            else *(u16*)(W + HLO + ROW(k) * HSTR + cc * 2) = l;
        }
        short8 Eh = *(const short8*)(W + (L & 15) * HSTR + (L >> 4) * 16);
        short8 El = *(const short8*)(W + HLO + (L & 15) * HSTR + (L >> 4) * 16);
#pragma unroll
        for (int nt = 0; nt < 2; ++nt) {
            short8 bh = *(const short8*)(ws + OFF_WT + nt * 1024 + L * 8);
            short8 bl = *(const short8*)(ws + OFF_WT + nt * 1024 + 512 + L * 8);
            f32x4 acc = {0.f, 0.f, 0.f, 0.f};
            acc = mfma3(Eh, El, bh, bl, acc);
#pragma unroll
            for (int rr = 0; rr < 4; ++rr)
                *(float*)(Sb + ((L >> 4) * 4 + rr) * SSTR + nt * 64 + (L & 15) * 4) = acc[rr];
        }
        float vbt = bt[cc];
#pragma unroll
        for (int k = 0; k < 14; ++k) {
            float xv = fmaxf(*(const float*)(Sb + ROW(k) * SSTR + cc * 4) + vbt, 0.f);
            u16 h, l;
            split2(xv, h, l);
            if (L < 32) *(u16*)(XS2 + ROW(k) * XS2S + cc * 2) = h;
            else *(u16*)(XS2 + XS2LO + ROW(k) * XS2S + cc * 2) = l;
        }
    }

    short8 Ah[3], Al[3];
    float pp[14], qq[14];

    // ---- init: x0 = h1 @ wi2 + bi2  (X: W, S: Sb, X back to W) ----
    writeX64_14(W, L, h1);
    loadA<2>(W, XS2, L, Ah, Al);
    lin_pass<2, 4>(ws, OFF_I, 0, Ah, Al, Sb, L);
    {
        float xh[14];
        readS14(Sb, L, xh);
        float vbi2 = bi2[L];
#pragma unroll
        for (int k = 0; k < 14; ++k) xh[k] += vbi2;
        writeX64_14(W, L, xh);
    }

    // ---- L1a (K=64): A from W, S in Sb ----
    loadA<2>(W, XS2, L, Ah, Al);
    lin_pass<2, 8>(ws, OFF_1A, 0, Ah, Al, Sb, L);
    readS14(Sb, L, pp);
    lin_pass<2, 8>(ws, OFF_1A, 4, Ah, Al, Sb, L);
    readS14(Sb, L, qq);
    float vb1a = b1a[L];
#pragma unroll
    for (int k = 0; k < 14; ++k) pp[k] = pp[k] + vb1a - qq[k];
    // ---- L1b (pipelined; X out -> W) ----
    edgeconv_pipe(ws, OFF_1B, W, H1, Sb, pp, qq, b1b[L], L);

    // ---- L2a (K=96: [x | xs]) ----
    loadA<3>(W, XS2, L, Ah, Al);
    lin_pass<3, 8>(ws, OFF_2A, 0, Ah, Al, Sb, L);
    readS14(Sb, L, pp);
    lin_pass<3, 8>(ws, OFF_2A, 4, Ah, Al, Sb, L);
    readS14(Sb, L, qq);
    float vb2a = b2a[L];
#pragma unroll
    for (int k = 0; k < 14; ++k) pp[k] = pp[k] + vb2a - qq[k];
    // ---- L2b ----
    edgeconv_pipe(ws, OFF_2B, W, H1, Sb, pp, qq, b2b[L], L);

    // ---- L3a (K=96) ----
    loadA<3>(W, XS2, L, Ah, Al);
    lin_pass<3, 8>(ws, OFF_3A, 0, Ah, Al, Sb, L);
    readS14(Sb, L, pp);
    lin_pass<3, 8>(ws, OFF_3A, 4, Ah, Al, Sb, L);
    readS14(Sb, L, qq);
    float vb3a = b3a[L];
#pragma unroll
    for (int k = 0; k < 14; ++k) pp[k] = pp[k] + vb3a - qq[k];

    // ---- L3b (64->3) via MFMA (pipelined) + max + /(std+1e-7) ----
    {
        short8 B0h = *(const short8*)(ws + OFF_3B + L * 8);
        short8 B0l = *(const short8*)(ws + OFF_3B + 512 + L * 8);
        short8 B1h = *(const short8*)(ws + OFF_3B + 1024 + L * 8);
        short8 B1l = *(const short8*)(ws + OFF_3B + 1536 + L * 8);
        stageH2(W, 0, pp, qq, L);
        short8 Ah0, Ah1, Al0, Al1;
        loadAH(W, L, Ah0, Ah1, Al0, Al1);
#pragma unroll
        for (int c = 0; c < 6; ++c) {
            char* Hn = ((c + 1) & 1) ? H1 : W;
            if (c < 5) stageH2(Hn, c + 1, pp, qq, L);
            f32x4 a1 = {0.f, 0.f, 0.f, 0.f}, a2 = {0.f, 0.f, 0.f, 0.f};
            a1 = mfma1(Ah0, B0h, a1);
            a2 = mfma1(Ah0, B0l, a2);
            a2 = mfma1(Al0, B0h, a2);
            a1 = mfma1(Ah1, B1h, a1);
            a2 = mfma1(Ah1, B1l, a2);
            a2 = mfma1(Al1, B1h, a2);
            if ((L & 15) < 3) {       // compact strip: row e (96), stride 16B, col 0..2
#pragma unroll
                for (int rr = 0; rr < 4; ++rr)
                    *(float*)(Sb + (c * 16 + (L >> 4) * 4 + rr) * 16 + (L & 15) * 4) = a1[rr] + a2[rr];
            }
            if (c < 5) loadAH(Hn, L, Ah0, Ah1, Al0, Al1);
        }
        if (L < 42) {                 // lanes 0-20: g0; 21-41: g1
            int gb = (L >= 21) ? 1 : 0;
            int ll = L - gb * 21;
            int i = ll / 3, col = ll - i * 3;
            int e0 = gb * 42 + i * 6;
            float m = -3.0e38f;
#pragma unroll
            for (int e6 = 0; e6 < 6; ++e6)
                m = fmaxf(m, *(const float*)(Sb + (e0 + e6) * 16 + col * 4));
            m += b3b[col];
            float tg = tt[g0 + gb];   // std uses t[n // 7]
            float stdv = sqrtf((exp2f(tg * 9.287712379549448f) - 1.0f) * 0.15533740282828987f);
            out[base0 * 3 + L] = m / (stdv + 1e-7f);   // contiguous 42 outputs
        }
    }
}

extern "C" void kernel_launch(void* const* d_in, const int* in_sizes, int n_in,
                              void* d_out, int out_size, void* d_ws, size_t ws_size,
                              hipStream_t stream) {
    const float* omega = (const float*)d_in[0];
    // d_in[1] edge_index unused (fixed fully-connected); d_in[3] num_objs == 7
    const float* tt  = (const float*)d_in[2];
    const float* Wf  = (const float*)d_in[4];
    const float* wi1 = (const float*)d_in[5];
    const float* bi1 = (const float*)d_in[6];
    const float* wi2 = (const float*)d_in[7];
    const float* bi2 = (const float*)d_in[8];
    const float* wt  = (const float*)d_in[9];
    const float* bt  = (const float*)d_in[10];
    const float* w1a = (const float*)d_in[11];
    const float* b1a = (const float*)d_in[12];
    const float* w1b = (const float*)d_in[13];
    const float* b1b = (const float*)d_in[14];
    const float* w2a = (const float*)d_in[15];
    const float* b2a = (const float*)d_in[16];
    const float* w2b = (const float*)d_in[17];
    const float* b2b = (const float*)d_in[18];
    const float* w3a = (const float*)d_in[19];
    const float* b3a = (const float*)d_in[20];
    const float* w3b = (const float*)d_in[21];
    const float* b3b = (const float*)d_in[22];
    u16* ws = (u16*)d_ws;   // needs 188416 bytes

    pack_kernel<<<dim3(92), dim3(128), 0, stream>>>(wi2, w1a, w2a, w3a, w1b, w2b, wt, w3b, ws);
    gnn_kernel<<<dim3(12500), dim3(128), 0, stream>>>(
        omega, tt, Wf, wi1, bi1, bi2, bt,
        b1a, b1b, b2a, b2b, b3a, b3b, ws, (float*)d_out);
}

// Round 13
// 417.447 us; speedup vs baseline: 1.3483x; 1.0182x over previous
//
#include <hip/hip_runtime.h>

// ScoreNetGNN: B=50000 graphs x 7 nodes, fully-connected (42 edges/graph).
// R6: MFMA pipeline (16x16x32 bf16 split hi+lo). R7: strides/LDS. R8: two
// graphs/wave. R9: 128-thr blocks. R11: two-chain accum + pipelined edgeconv.
// R12 (best, 425us): truncation-split, resident edge B-frags. R13:
//  (1) pack_kernel parallelized 8x (gridDim.y = element j; was latency-bound
//      at 92 blocks and cost ~25-40us of the bench-vs-counter gap);
//  (2) H staged as PACKED u32 (lo<<16|hi) @ row stride 272: one ds_write_b32
//      per element (was 2x ds_write_b16), read back with v_perm_b32
//      de-interleave -> DS-pipe relief (-288 DS instrs/pair).
// f32 I/O hardcoded (R3 counters: WRITE_SIZE = 4 B/elem).

#define NB 50000

typedef unsigned short u16;
typedef unsigned int u32;
typedef short short8 __attribute__((ext_vector_type(8)));
typedef float f32x4 __attribute__((ext_vector_type(4)));

// d_ws fragment offsets (u16 units). frag stride 1024 u16 (hi 512 | lo 512),
// lane entry = 8 u16 (16B). Total 94208 u16 = 188416 bytes.
#define OFF_I  0
#define OFF_1A 8192
#define OFF_2A 24576
#define OFF_3A 49152
#define OFF_1B 73728
#define OFF_2B 81920
#define OFF_WT 90112
#define OFF_3B 92160

// LDS per-wave geometry (bytes). W/H1 dual-use regions (4608B each):
//  - as X: 16 rows x 64 bf16 @ stride 144, hi [0,2304) lo [2304,4608)
//  - as H: 16 rows x 64 packed u32 @ stride 272 (68 dw -> <=2-way, free)
// XS2: xs strip 16 x 32 bf16 @ stride 72, write-once. Sb: f32 C @ stride 264.
#define HSTR 144
#define HLO  2304
#define H2S  272
#define XS2S 72
#define XS2LO 1152
#define SSTR 264
#define WREG 15744   // W 4608 + XS2 2304 + H1 4608 + Sb 4224

__device__ __forceinline__ float b2f(u16 u) {
    return __uint_as_float(((u32)u) << 16);
}
__device__ __forceinline__ u16 f2b(float f) {
    u32 u = __float_as_uint(f);
    u += 0x7FFFu + ((u >> 16) & 1u);   // RNE
    return (u16)(u >> 16);
}
// split v into bf16 hi (truncated, v-hi exact) + bf16 lo (RNE of residual)
__device__ __forceinline__ void split2(float v, u16& h, u16& l) {
    u32 u = __float_as_uint(v);
    h = (u16)(u >> 16);
    float d = v - __uint_as_float(u & 0xffff0000u);
    l = f2b(d);
}
// packed u32: low16 = hi(trunc), high16 = lo(RNE)
__device__ __forceinline__ u32 splitpack(float v) {
    u32 u = __float_as_uint(v);
    float d = v - __uint_as_float(u & 0xffff0000u);
    u32 r = __float_as_uint(d);
    r += 0x7FFFu + ((r >> 16) & 1u);
    return __builtin_amdgcn_perm(r, u, 0x07060302);  // [u.b2,u.b3,r.b2,r.b3]
}
__device__ __forceinline__ float bcast(float v, int l) {
    return __uint_as_float(__builtin_amdgcn_readlane(__float_as_uint(v), l));
}

// ---- setup: pack weights into split-bf16 MFMA B-fragments ----
// grid (92, 8): blockIdx.y = element j within lane entry; 128 thr = half x lane.
__global__ __launch_bounds__(128) void pack_kernel(
    const float* __restrict__ wi2, const float* __restrict__ w1a,
    const float* __restrict__ w2a, const float* __restrict__ w3a,
    const float* __restrict__ w1b, const float* __restrict__ w2b,
    const float* __restrict__ wt,  const float* __restrict__ w3b,
    u16* __restrict__ ws)
{
    int blk = blockIdx.x;
    int j    = blockIdx.y;
    int half = threadIdx.x >> 6;          // 0 = hi, 1 = lo
    int lane = threadIdx.x & 63;
    float v;
    u16* dst;
    if (blk < 88) {
        const float* src; int NT, qoff, obase, frag;
        if (blk < 8)       { src = wi2; NT = 4; qoff = 0;  obase = OFF_I;  frag = blk;      }
        else if (blk < 24) { src = w1a; NT = 8; qoff = 64; obase = OFF_1A; frag = blk - 8;  }
        else if (blk < 48) { src = w2a; NT = 8; qoff = 96; obase = OFF_2A; frag = blk - 24; }
        else if (blk < 72) { src = w3a; NT = 8; qoff = 96; obase = OFF_3A; frag = blk - 48; }
        else if (blk < 80) { src = w1b; NT = 4; qoff = 0;  obase = OFF_1B; frag = blk - 72; }
        else               { src = w2b; NT = 4; qoff = 0;  obase = OFF_2B; frag = blk - 80; }
        int kt = frag / NT, nt = frag % NT;
        int k = kt * 32 + (lane >> 4) * 8 + j;
        int n = nt * 16 + (lane & 15);
        int idx = (n < 64) ? (k * 64 + n) : ((qoff + k) * 64 + (n - 64));
        v = src[idx];
        dst = ws + obase + frag * 1024 + half * 512 + lane * 8 + j;
    } else if (blk < 90) {               // wt (32,32): 2 n-frags
        int frag = blk - 88;
        int k = (lane >> 4) * 8 + j;
        int n = frag * 16 + (lane & 15);
        v = wt[k * 32 + n];
        dst = ws + OFF_WT + frag * 1024 + half * 512 + lane * 8 + j;
    } else {                             // w3b (64,3): 2 k-frags, cols 3..15 = 0
        int frag = blk - 90;
        int k = frag * 32 + (lane >> 4) * 8 + j;
        int n = lane & 15;
        v = (n < 3) ? w3b[k * 3 + n] : 0.f;
        dst = ws + OFF_3B + frag * 1024 + half * 512 + lane * 8 + j;
    }
    u16 hi = f2b(v);
    *dst = (half == 0) ? hi : f2b(v - b2f(hi));
}

__device__ __forceinline__ f32x4 mfma1(short8 a, short8 b, f32x4 acc) {
    return __builtin_amdgcn_mfma_f32_16x16x32_bf16(a, b, acc, 0, 0, 0);
}
__device__ __forceinline__ f32x4 mfma3(short8 ah, short8 al, short8 bh, short8 bl, f32x4 acc) {
    acc = mfma1(ah, bh, acc);
    acc = mfma1(ah, bl, acc);
    acc = mfma1(al, bh, acc);
    return acc;   // lo*lo dropped
}

// node k (0..13) -> row (g0 rows 0-6, g1 rows 8-14; rows 7,15 stale/unread)
#define ROW(k) ((k) < 7 ? (k) : (k) + 1)

// write 14 node values (64 cols) into region G as X (bf16 hi/lo planes)
__device__ __forceinline__ void writeX64_14(char* G, int L, const float* v) {
#pragma unroll
    for (int k = 0; k < 14; ++k) {
        int r = ROW(k);
        u16 h, l;
        split2(v[k], h, l);
        *(u16*)(G + r * HSTR + L * 2) = h;
        *(u16*)(G + HLO + r * HSTR + L * 2) = l;
    }
}
// A-frags: kt 0,1 from G (cols 0-63); kt 2 from XS2 strip (cols 64-95)
template<int KT>
__device__ __forceinline__ void loadA(const char* G, const char* XS2, int L,
                                      short8* Ah, short8* Al) {
#pragma unroll
    for (int kt = 0; kt < KT; ++kt) {
        if (kt < 2) {
            Ah[kt] = *(const short8*)(G + (L & 15) * HSTR + kt * 64 + (L >> 4) * 16);
            Al[kt] = *(const short8*)(G + HLO + (L & 15) * HSTR + kt * 64 + (L >> 4) * 16);
        } else {
            Ah[kt] = *(const short8*)(XS2 + (L & 15) * XS2S + (L >> 4) * 16);
            Al[kt] = *(const short8*)(XS2 + XS2LO + (L & 15) * XS2S + (L >> 4) * 16);
        }
    }
}
// One 4-N-tile GEMM pass: S[row][col 0..63] = A(16xK) @ B(Kx64).
template<int KT, int NT>
__device__ __forceinline__ void lin_pass(const u16* __restrict__ ws, int off, int nt0,
                                         const short8* Ah, const short8* Al,
                                         char* Sg, int L) {
#pragma unroll
    for (int ntc = 0; ntc < 4; ++ntc) {
        f32x4 a1 = {0.f, 0.f, 0.f, 0.f}, a2 = {0.f, 0.f, 0.f, 0.f};
#pragma unroll
        for (int kt = 0; kt < KT; ++kt) {
            int f = kt * NT + nt0 + ntc;
            short8 bh = *(const short8*)(ws + off + f * 1024 + L * 8);
            short8 bl = *(const short8*)(ws + off + f * 1024 + 512 + L * 8);
            a1 = mfma1(Ah[kt], bh, a1);
            a2 = mfma1(Ah[kt], bl, a2);
            a2 = mfma1(Al[kt], bh, a2);
        }
#pragma unroll
        for (int rr = 0; rr < 4; ++rr)   // C: row=(L>>4)*4+rr, col=ntc*16+(L&15)
            *(float*)(Sg + ((L >> 4) * 4 + rr) * SSTR + ntc * 64 + (L & 15) * 4) = a1[rr] + a2[rr];
    }
}
__device__ __forceinline__ void readS14(const char* Sg, int L, float* o) {
#pragma unroll
    for (int k = 0; k < 14; ++k) o[k] = *(const float*)(Sg + ROW(k) * SSTR + L * 4);
}
// stage 16 edge rows (chunk c of 6; 84 real edges) as PACKED u32 per element
__device__ __forceinline__ void stageH2(char* G, int c, const float* pp, const float* qq, int L) {
#pragma unroll
    for (int r = 0; r < 16; ++r) {
        int e = c * 16 + r;
        if (e < 84) {
            int gb = (e >= 42) ? 1 : 0;
            int el = e - gb * 42;
            int i = el / 6, jj = el - i * 6;
            int j = jj + (jj >= i);
            float hv = fmaxf(pp[gb * 7 + i] + qq[gb * 7 + j], 0.f);
            *(u32*)(G + r * H2S + L * 4) = splitpack(hv);
        }
    }
}
// de-interleave 4 packed u32 -> hi short8-half (2 u32) and lo half
__device__ __forceinline__ void unpack4(const uint4& a, u32* ho, u32* lo) {
    ho[0] = __builtin_amdgcn_perm(a.y, a.x, 0x05040100);
    ho[1] = __builtin_amdgcn_perm(a.w, a.z, 0x05040100);
    lo[0] = __builtin_amdgcn_perm(a.y, a.x, 0x07060302);
    lo[1] = __builtin_amdgcn_perm(a.w, a.z, 0x07060302);
}
__device__ __forceinline__ void loadAH(const char* G, int L,
                                       short8& Ah0, short8& Ah1, short8& Al0, short8& Al1) {
    const char* base = G + (L & 15) * H2S + (L >> 4) * 32;
    uint4 a0 = *(const uint4*)(base);
    uint4 a1 = *(const uint4*)(base + 16);
    uint4 b0 = *(const uint4*)(base + 128);
    uint4 b1 = *(const uint4*)(base + 144);
    union { u32 u[4]; short8 s; } h0, h1, l0, l1;
    unpack4(a0, &h0.u[0], &l0.u[0]);
    unpack4(a1, &h0.u[2], &l0.u[2]);
    unpack4(b0, &h1.u[0], &l1.u[0]);
    unpack4(b1, &h1.u[2], &l1.u[2]);
    Ah0 = h0.s; Al0 = l0.s; Ah1 = h1.s; Al1 = l1.s;
}
// fold chunk cc's S rows into per-node running max (column L)
__device__ __forceinline__ void maxread(const char* Sb, int cc, float* mx, int L) {
#pragma unroll
    for (int r = 0; r < 16; ++r) {
        int e = cc * 16 + r;
        if (e < 84) {
            int gb = (e >= 42) ? 1 : 0;
            int i = (e - gb * 42) / 6;
            float sv = *(const float*)(Sb + r * SSTR + L * 4);
            mx[gb * 7 + i] = fmaxf(mx[gb * 7 + i], sv);
        }
    }
}

// EdgeConv second linear (64->64) + max-agg + bias + relu via MFMA,
// software-pipelined across 6 chunks with double-buffered H (W / H1).
// B-frags resident in registers. Output X written back into W.
__device__ __forceinline__ void edgeconv_pipe(const u16* __restrict__ ws, int offB,
                                              char* W, char* H1, char* Sb,
                                              const float* pp, const float* qq,
                                              float vb, int L) {
    short8 Bh[8], Bl[8];            // f = kt*4+nt, resident across all 6 chunks
#pragma unroll
    for (int f = 0; f < 8; ++f) {
        Bh[f] = *(const short8*)(ws + offB + f * 1024 + L * 8);
        Bl[f] = *(const short8*)(ws + offB + f * 1024 + 512 + L * 8);
    }
    float mx[14];
#pragma unroll
    for (int k = 0; k < 14; ++k) mx[k] = -3.0e38f;
    stageH2(W, 0, pp, qq, L);
    short8 Ah0, Ah1, Al0, Al1;
    loadAH(W, L, Ah0, Ah1, Al0, Al1);
#pragma unroll
    for (int c = 0; c < 6; ++c) {
        char* Hn = ((c + 1) & 1) ? H1 : W;
        if (c < 5) stageH2(Hn, c + 1, pp, qq, L);   // overlaps chunk-c MFMAs
        if (c > 0) maxread(Sb, c - 1, mx, L);       // before S is overwritten
#pragma unroll
        for (int nt = 0; nt < 4; ++nt) {
            f32x4 a1 = {0.f, 0.f, 0.f, 0.f}, a2 = {0.f, 0.f, 0.f, 0.f};
            a1 = mfma1(Ah0, Bh[nt], a1);
            a2 = mfma1(Ah0, Bl[nt], a2);
            a2 = mfma1(Al0, Bh[nt], a2);
            a1 = mfma1(Ah1, Bh[4 + nt], a1);
            a2 = mfma1(Ah1, Bl[4 + nt], a2);
            a2 = mfma1(Al1, Bh[4 + nt], a2);
#pragma unroll
            for (int rr = 0; rr < 4; ++rr)
                *(float*)(Sb + ((L >> 4) * 4 + rr) * SSTR + nt * 64 + (L & 15) * 4) = a1[rr] + a2[rr];
        }
        if (c < 5) loadAH(Hn, L, Ah0, Ah1, Al0, Al1);   // prefetch next chunk
    }
    maxread(Sb, 5, mx, L);
    float xo[14];
#pragma unroll
    for (int k = 0; k < 14; ++k) xo[k] = fmaxf(mx[k] + vb, 0.f);
    writeX64_14(W, L, xo);
}

__global__ __launch_bounds__(128) void gnn_kernel(
    const float* __restrict__ omega, const float* __restrict__ tt, const float* __restrict__ Wf,
    const float* __restrict__ wi1, const float* __restrict__ bi1, const float* __restrict__ bi2,
    const float* __restrict__ bt,
    const float* __restrict__ b1a, const float* __restrict__ b1b,
    const float* __restrict__ b2a, const float* __restrict__ b2b,
    const float* __restrict__ b3a, const float* __restrict__ b3b,
    const u16* __restrict__ ws, float* __restrict__ out)
{
    __shared__ __align__(16) char smem[2 * WREG];   // 31488 B/block
    const int L   = threadIdx.x & 63;
    const int wav = threadIdx.x >> 6;
    const int p   = blockIdx.x * 2 + wav;    // graph pair id, grid covers 25000
    const int g0  = p * 2;
    const int base0 = g0 * 7;                // g1 nodes start at base0+7
    char* W   = smem + wav * WREG;
    char* XS2 = W + 4608;
    char* H1  = W + 6912;
    char* Sb  = W + 11520;

    // ---- h1 = relu(omega@wi1 + bi1), both graphs (42 contiguous coords) ----
    float omv = (L < 42) ? omega[base0 * 3 + L] : 0.f;
    float vwi10 = wi1[L], vwi11 = wi1[64 + L], vwi12 = wi1[128 + L];
    float vbi1 = bi1[L];
    float h1[14];
#pragma unroll
    for (int k = 0; k < 14; ++k) {
        float a0 = bcast(omv, 3 * k), a1 = bcast(omv, 3 * k + 1), a2 = bcast(omv, 3 * k + 2);
        h1[k] = fmaxf(fmaf(a0, vwi10, fmaf(a1, vwi11, fmaf(a2, vwi12, vbi1))), 0.f);
    }

    // ---- time embedding via MFMA (tile-bug: node n uses t[n % B]) ----
    // E staged in W (bf16 planes, cols 0-31); C -> Sb; xs written ONCE to XS2.
    {
        int cc = L & 31;
        float vwf = Wf[cc & 15] * 6.283185307179586f;
        int tb = base0 - (base0 / NB) * NB;        // base0 % NB
#pragma unroll
        for (int k = 0; k < 14; ++k) {
            int ti = tb + k; if (ti >= NB) ti -= NB;
            float pj = tt[ti] * vwf;
            float remb = fmaxf((cc < 16) ? __sinf(pj) : __cosf(pj), 0.f);
            u16 h, l;
            split2(remb, h, l);
            if (L < 32) *(u16*)(W + ROW(k) * HSTR + cc * 2) = h;
            else *(u16*)(W + HLO + ROW(k) * HSTR + cc * 2) = l;
        }
        short8 Eh = *(const short8*)(W + (L & 15) * HSTR + (L >> 4) * 16);
        short8 El = *(const short8*)(W + HLO + (L & 15) * HSTR + (L >> 4) * 16);
#pragma unroll
        for (int nt = 0; nt < 2; ++nt) {
            short8 bh = *(const short8*)(ws + OFF_WT + nt * 1024 + L * 8);
            short8 bl = *(const short8*)(ws + OFF_WT + nt * 1024 + 512 + L * 8);
            f32x4 acc = {0.f, 0.f, 0.f, 0.f};
            acc = mfma3(Eh, El, bh, bl, acc);
#pragma unroll
            for (int rr = 0; rr < 4; ++rr)
                *(float*)(Sb + ((L >> 4) * 4 + rr) * SSTR + nt * 64 + (L & 15) * 4) = acc[rr];
        }
        float vbt = bt[cc];
#pragma unroll
        for (int k = 0; k < 14; ++k) {
            float xv = fmaxf(*(const float*)(Sb + ROW(k) * SSTR + cc * 4) + vbt, 0.f);
            u16 h, l;
            split2(xv, h, l);
            if (L < 32) *(u16*)(XS2 + ROW(k) * XS2S + cc * 2) = h;
            else *(u16*)(XS2 + XS2LO + ROW(k) * XS2S + cc * 2) = l;
        }
    }

    short8 Ah[3], Al[3];
    float pp[14], qq[14];

    // ---- init: x0 = h1 @ wi2 + bi2  (X: W, S: Sb, X back to W) ----
    writeX64_14(W, L, h1);
    loadA<2>(W, XS2, L, Ah, Al);
    lin_pass<2, 4>(ws, OFF_I, 0, Ah, Al, Sb, L);
    {
        float xh[14];
        readS14(Sb, L, xh);
        float vbi2 = bi2[L];
#pragma unroll
        for (int k = 0; k < 14; ++k) xh[k] += vbi2;
        writeX64_14(W, L, xh);
    }

    // ---- L1a (K=64): A from W, S in Sb ----
    loadA<2>(W, XS2, L, Ah, Al);
    lin_pass<2, 8>(ws, OFF_1A, 0, Ah, Al, Sb, L);
    readS14(Sb, L, pp);
    lin_pass<2, 8>(ws, OFF_1A, 4, Ah, Al, Sb, L);
    readS14(Sb, L, qq);
    float vb1a = b1a[L];
#pragma unroll
    for (int k = 0; k < 14; ++k) pp[k] = pp[k] + vb1a - qq[k];
    // ---- L1b (pipelined; X out -> W) ----
    edgeconv_pipe(ws, OFF_1B, W, H1, Sb, pp, qq, b1b[L], L);

    // ---- L2a (K=96: [x | xs]) ----
    loadA<3>(W, XS2, L, Ah, Al);
    lin_pass<3, 8>(ws, OFF_2A, 0, Ah, Al, Sb, L);
    readS14(Sb, L, pp);
    lin_pass<3, 8>(ws, OFF_2A, 4, Ah, Al, Sb, L);
    readS14(Sb, L, qq);
    float vb2a = b2a[L];
#pragma unroll
    for (int k = 0; k < 14; ++k) pp[k] = pp[k] + vb2a - qq[k];
    // ---- L2b ----
    edgeconv_pipe(ws, OFF_2B, W, H1, Sb, pp, qq, b2b[L], L);

    // ---- L3a (K=96) ----
    loadA<3>(W, XS2, L, Ah, Al);
    lin_pass<3, 8>(ws, OFF_3A, 0, Ah, Al, Sb, L);
    readS14(Sb, L, pp);
    lin_pass<3, 8>(ws, OFF_3A, 4, Ah, Al, Sb, L);
    readS14(Sb, L, qq);
    float vb3a = b3a[L];
#pragma unroll
    for (int k = 0; k < 14; ++k) pp[k] = pp[k] + vb3a - qq[k];

    // ---- L3b (64->3) via MFMA (pipelined) + max + /(std+1e-7) ----
    {
        short8 B0h = *(const short8*)(ws + OFF_3B + L * 8);
        short8 B0l = *(const short8*)(ws + OFF_3B + 512 + L * 8);
        short8 B1h = *(const short8*)(ws + OFF_3B + 1024 + L * 8);
        short8 B1l = *(const short8*)(ws + OFF_3B + 1536 + L * 8);
        stageH2(W, 0, pp, qq, L);
        short8 Ah0, Ah1, Al0, Al1;
        loadAH(W, L, Ah0, Ah1, Al0, Al1);
#pragma unroll
        for (int c = 0; c < 6; ++c) {
            char* Hn = ((c + 1) & 1) ? H1 : W;
            if (c < 5) stageH2(Hn, c + 1, pp, qq, L);
            f32x4 a1 = {0.f, 0.f, 0.f, 0.f}, a2 = {0.f, 0.f, 0.f, 0.f};
            a1 = mfma1(Ah0, B0h, a1);
            a2 = mfma1(Ah0, B0l, a2);
            a2 = mfma1(Al0, B0h, a2);
            a1 = mfma1(Ah1, B1h, a1);
            a2 = mfma1(Ah1, B1l, a2);
            a2 = mfma1(Al1, B1h, a2);
            if ((L & 15) < 3) {       // compact strip: row e (96), stride 16B, col 0..2
#pragma unroll
                for (int rr = 0; rr < 4; ++rr)
                    *(float*)(Sb + (c * 16 + (L >> 4) * 4 + rr) * 16 + (L & 15) * 4) = a1[rr] + a2[rr];
            }
            if (c < 5) loadAH(Hn, L, Ah0, Ah1, Al0, Al1);
        }
        if (L < 42) {                 // lanes 0-20: g0; 21-41: g1
            int gb = (L >= 21) ? 1 : 0;
            int ll = L - gb * 21;
            int i = ll / 3, col = ll - i * 3;
            int e0 = gb * 42 + i * 6;
            float m = -3.0e38f;
#pragma unroll
            for (int e6 = 0; e6 < 6; ++e6)
                m = fmaxf(m, *(const float*)(Sb + (e0 + e6) * 16 + col * 4));
            m += b3b[col];
            float tg = tt[g0 + gb];   // std uses t[n // 7]
            float stdv = sqrtf((exp2f(tg * 9.287712379549448f) - 1.0f) * 0.15533740282828987f);
            out[base0 * 3 + L] = m / (stdv + 1e-7f);   // contiguous 42 outputs
        }
    }
}

extern "C" void kernel_launch(void* const* d_in, const int* in_sizes, int n_in,
                              void* d_out, int out_size, void* d_ws, size_t ws_size,
                              hipStream_t stream) {
    const float* omega = (const float*)d_in[0];
    // d_in[1] edge_index unused (fixed fully-connected); d_in[3] num_objs == 7
    const float* tt  = (const float*)d_in[2];
    const float* Wf  = (const float*)d_in[4];
    const float* wi1 = (const float*)d_in[5];
    const float* bi1 = (const float*)d_in[6];
    const float* wi2 = (const float*)d_in[7];
    const float* bi2 = (const float*)d_in[8];
    const float* wt  = (const float*)d_in[9];
    const float* bt  = (const float*)d_in[10];
    const float* w1a = (const float*)d_in[11];
    const float* b1a = (const float*)d_in[12];
    const float* w1b = (const float*)d_in[13];
    const float* b1b = (const float*)d_in[14];
    const float* w2a = (const float*)d_in[15];
    const float* b2a = (const float*)d_in[16];
    const float* w2b = (const float*)d_in[17];
    const float* b2b = (const float*)d_in[18];
    const float* w3a = (const float*)d_in[19];
    const float* b3a = (const float*)d_in[20];
    const float* w3b = (const float*)d_in[21];
    const float* b3b = (const float*)d_in[22];
    u16* ws = (u16*)d_ws;   // needs 188416 bytes

    pack_kernel<<<dim3(92, 8), dim3(128), 0, stream>>>(wi2, w1a, w2a, w3a, w1b, w2b, wt, w3b, ws);
    gnn_kernel<<<dim3(12500), dim3(128), 0, stream>>>(
        omega, tt, Wf, wi1, bi1, bi2, bt,
        b1a, b1b, b2a, b2b, b3a, b3b, ws, (float*)d_out);
}